// Round 1
// baseline (3388.630 us; speedup 1.0000x reference)
//
#include <hip/hip_runtime.h>

#define N_NODES 100000
#define N_EDGES 1000000
#define HID 64

// x[n] = node_emb[z[n]]  (16 threads per node, float4 each)
__global__ __launch_bounds__(256) void gather_kernel(
    const float* __restrict__ node_emb, const int* __restrict__ z,
    float* __restrict__ x)
{
    int t = blockIdx.x * 256 + threadIdx.x;
    int n = t >> 4, c = t & 15;
    if (n >= N_NODES) return;
    int zi = z[n];
    float4 v = ((const float4*)(node_emb + (size_t)zi * HID))[c];
    ((float4*)(x + (size_t)n * HID))[c] = v;
}

// agg[dst[e]] += relu(x[src[e]] + edge_attr[e])   (16 threads/edge, float4)
__global__ __launch_bounds__(256) void scatter_kernel(
    const float* __restrict__ x, const float* __restrict__ ea,
    const int* __restrict__ src, const int* __restrict__ dst,
    float* __restrict__ agg)
{
    int t = blockIdx.x * 256 + threadIdx.x;
    int e = t >> 4, c = t & 15;
    if (e >= N_EDGES) return;
    int s = src[e], d = dst[e];
    float4 a = ((const float4*)(ea + (size_t)e * HID))[c];
    float4 v = ((const float4*)(x + (size_t)s * HID))[c];
    float* p = agg + (size_t)d * HID + (c << 2);
    atomicAdd(p + 0, fmaxf(v.x + a.x, 0.f));
    atomicAdd(p + 1, fmaxf(v.y + a.y, 0.f));
    atomicAdd(p + 2, fmaxf(v.z + a.z, 0.f));
    atomicAdd(p + 3, fmaxf(v.w + a.w, 0.f));
}

// Per-node 2-layer MLP + residual.
// out = agg + x ; h1 = relu(out@W1^T + b1) ; h2 = h1@W2^T + b2 ;
// if last_relu: h2 = relu(h2) ; xout = h2 + x
// Thread-per-node. W rows broadcast from global (L1-resident, 16KB/layer).
// h1 goes through an LDS row (pitch 65 -> conflict-free) to turn the
// dynamically-indexed layer-1 output into constant-indexed layer-2 input.
__global__ __launch_bounds__(128) void mlp_kernel(
    const float* __restrict__ xin, const float* __restrict__ agg,
    const float* __restrict__ W1, const float* __restrict__ b1,
    const float* __restrict__ W2, const float* __restrict__ b2,
    float* __restrict__ xout, int last_relu)
{
    __shared__ float sh1[128 * 65];
    int n = blockIdx.x * 128 + threadIdx.x;
    if (n >= N_NODES) return;

    float out[HID];
    const float4* ap = (const float4*)(agg + (size_t)n * HID);
    const float4* xp = (const float4*)(xin + (size_t)n * HID);
#pragma unroll
    for (int c = 0; c < 16; ++c) {
        float4 a = ap[c], b = xp[c];
        out[4*c+0] = a.x + b.x;
        out[4*c+1] = a.y + b.y;
        out[4*c+2] = a.z + b.z;
        out[4*c+3] = a.w + b.w;
    }

    float* myh = &sh1[threadIdx.x * 65];
    for (int j = 0; j < HID; ++j) {
        const float4* wp = (const float4*)(W1 + (size_t)j * HID);
        float acc = b1[j];
#pragma unroll
        for (int c = 0; c < 16; ++c) {
            float4 w = wp[c];
            acc += out[4*c+0]*w.x + out[4*c+1]*w.y
                 + out[4*c+2]*w.z + out[4*c+3]*w.w;
        }
        myh[j] = fmaxf(acc, 0.f);
    }

    float h1[HID];
#pragma unroll
    for (int k = 0; k < HID; ++k) h1[k] = myh[k];

    const float* xrow = xin + (size_t)n * HID;
    float* orow = xout + (size_t)n * HID;
    for (int j = 0; j < HID; ++j) {
        const float4* wp = (const float4*)(W2 + (size_t)j * HID);
        float acc = b2[j];
#pragma unroll
        for (int c = 0; c < 16; ++c) {
            float4 w = wp[c];
            acc += h1[4*c+0]*w.x + h1[4*c+1]*w.y
                 + h1[4*c+2]*w.z + h1[4*c+3]*w.w;
        }
        if (last_relu) acc = fmaxf(acc, 0.f);
        orow[j] = acc + xrow[j];
    }
}

extern "C" void kernel_launch(void* const* d_in, const int* in_sizes, int n_in,
                              void* d_out, int out_size, void* d_ws, size_t ws_size,
                              hipStream_t stream) {
    const float* node_emb = (const float*)d_in[0];
    const float* W1 = (const float*)d_in[1];
    const float* b1 = (const float*)d_in[2];
    const float* W2 = (const float*)d_in[3];
    const float* b2 = (const float*)d_in[4];
    const float* ea = (const float*)d_in[5];
    const int* z = (const int*)d_in[6];
    const int* ei = (const int*)d_in[7];
    const int* src = ei;            // edge_index[0] = message sender
    const int* dst = ei + N_EDGES;  // edge_index[1] = aggregation target

    float* xout_final = (float*)d_out;
    float* xa  = (float*)d_ws;                                  // 25.6 MB
    float* agg = (float*)d_ws + (size_t)N_NODES * HID;          // 25.6 MB

    const size_t feat_bytes = (size_t)N_NODES * HID * sizeof(float);
    const int scatter_blocks = (N_EDGES * 16) / 256;   // 62500
    const int gather_blocks  = (N_NODES * 16) / 256;   // 6250
    const int mlp_blocks     = (N_NODES + 127) / 128;

    // x = node_emb[z]
    gather_kernel<<<gather_blocks, 256, 0, stream>>>(node_emb, z, xa);

    // conv 0: xa -> d_out
    hipMemsetAsync(agg, 0, feat_bytes, stream);
    scatter_kernel<<<scatter_blocks, 256, 0, stream>>>(xa, ea, src, dst, agg);
    mlp_kernel<<<mlp_blocks, 128, 0, stream>>>(xa, agg, W1, b1, W2, b2,
                                               xout_final, 1);
    // conv 1: d_out -> xa
    hipMemsetAsync(agg, 0, feat_bytes, stream);
    scatter_kernel<<<scatter_blocks, 256, 0, stream>>>(xout_final, ea, src, dst, agg);
    mlp_kernel<<<mlp_blocks, 128, 0, stream>>>(xout_final, agg,
                                               W1 + 4096, b1 + 64,
                                               W2 + 4096, b2 + 64, xa, 1);
    // conv 2: xa -> d_out (no trailing relu)
    hipMemsetAsync(agg, 0, feat_bytes, stream);
    scatter_kernel<<<scatter_blocks, 256, 0, stream>>>(xa, ea, src, dst, agg);
    mlp_kernel<<<mlp_blocks, 128, 0, stream>>>(xa, agg,
                                               W1 + 8192, b1 + 128,
                                               W2 + 8192, b2 + 128,
                                               xout_final, 0);
}

// Round 3
// 1141.433 us; speedup vs baseline: 2.9688x; 2.9688x over previous
//
#include <hip/hip_runtime.h>

#define N_NODES 100000
#define N_EDGES 1000000
#define HID 64

// x[n] = node_emb[z[n]]  (16 threads per node, float4 each)
__global__ __launch_bounds__(256) void gather_kernel(
    const float* __restrict__ node_emb, const int* __restrict__ z,
    float* __restrict__ x)
{
    int t = blockIdx.x * 256 + threadIdx.x;
    int n = t >> 4, c = t & 15;
    if (n >= N_NODES) return;
    int zi = z[n];
    float4 v = ((const float4*)(node_emb + (size_t)zi * HID))[c];
    ((float4*)(x + (size_t)n * HID))[c] = v;
}

// offs[dst[e]] += 1  (degree histogram; offs pre-zeroed)
__global__ __launch_bounds__(256) void hist_kernel(
    const int* __restrict__ dst, int* __restrict__ offs)
{
    int e = blockIdx.x * 256 + threadIdx.x;
    if (e < N_EDGES) atomicAdd(&offs[dst[e]], 1);
}

// single-block exclusive scan of offs[N_NODES], in place.
// Results are published with atomicExch so the downstream atomicAdd
// cursor RMW (fill_kernel, possibly other XCD) never RMWs a stale value:
// atomic->atomic stays at the coherent point.
__global__ __launch_bounds__(1024) void scan_kernel(int* __restrict__ offs)
{
    __shared__ int wsum[16];
    int tid = threadIdx.x, lane = tid & 63, wid = tid >> 6;
    int running = 0;
    const int chunks = (N_NODES + 1023) / 1024;
    for (int ch = 0; ch < chunks; ++ch) {
        int i = ch * 1024 + tid;
        int v = (i < N_NODES) ? offs[i] : 0;
        int s = v;
#pragma unroll
        for (int d = 1; d < 64; d <<= 1) {
            int t = __shfl_up(s, (unsigned)d, 64);
            if (lane >= d) s += t;
        }
        if (lane == 63) wsum[wid] = s;
        __syncthreads();
        if (wid == 0) {
            int w = (lane < 16) ? wsum[lane] : 0;
#pragma unroll
            for (int d = 1; d < 16; d <<= 1) {
                int t = __shfl_up(w, (unsigned)d, 64);
                if (lane >= d) w += t;
            }
            if (lane < 16) wsum[lane] = w;
        }
        __syncthreads();
        int woff = (wid == 0) ? 0 : wsum[wid - 1];
        int total = wsum[15];
        if (i < N_NODES) atomicExch(&offs[i], running + woff + s - v); // exclusive
        running += total;
        __syncthreads();
    }
}

// eid2[slot] = (e, src[e]); offs becomes END offsets after this
// (start[n] = offs[n-1] afterwards, start[0] = 0).
__global__ __launch_bounds__(256) void fill_kernel(
    const int* __restrict__ src, const int* __restrict__ dst,
    int* __restrict__ offs, int2* __restrict__ eid2)
{
    int e = blockIdx.x * 256 + threadIdx.x;
    if (e < N_EDGES) {
        int d = dst[e];
        int pos = atomicAdd(&offs[d], 1);
        eid2[pos] = make_int2(e, src[e]);
    }
}

// Canonicalize each node's slot range to ascending edge-id order so the
// aggregation sum order is launch-invariant (fill's atomic cursor order is
// not). Wave per node, 64-lane bitonic sort, INT_MAX padding. Degrees are
// ~Poisson(10); P(deg>64) ~ 1e-40 — such nodes are left in cursor order.
__global__ __launch_bounds__(256) void sort_kernel(
    const int* __restrict__ offs, int2* __restrict__ eid2)
{
    int gt = blockIdx.x * 256 + threadIdx.x;
    int n = gt >> 6;
    int lane = threadIdx.x & 63;
    if (n >= N_NODES) return;                 // wave-uniform
    int start = (n == 0) ? 0 : offs[n - 1];
    int end = offs[n];
    int deg = end - start;
    if (deg <= 1 || deg > 64) return;         // wave-uniform
    int ke = 0x7fffffff, vs = 0;
    if (lane < deg) { int2 t = eid2[start + lane]; ke = t.x; vs = t.y; }
#pragma unroll
    for (int k = 2; k <= 64; k <<= 1) {
        for (int j = k >> 1; j > 0; j >>= 1) {
            int partner = lane ^ j;
            int ke2 = __shfl(ke, partner, 64);
            int vs2 = __shfl(vs, partner, 64);
            bool up = ((lane & k) == 0);
            bool takemin = ((lane < partner) == up);
            bool sw = takemin ? (ke2 < ke) : (ke2 > ke);
            if (sw) { ke = ke2; vs = vs2; }
        }
    }
    if (lane < deg) eid2[start + lane] = make_int2(ke, vs);
}

// Wave-per-node aggregation: lane c = channel c. No atomics.
// agg[n][c] = sum over incoming edges of relu(x[src][c] + ea[e][c])
__global__ __launch_bounds__(256) void agg_kernel(
    const float* __restrict__ x, const float* __restrict__ ea,
    const int2* __restrict__ eid2, const int* __restrict__ offs,
    float* __restrict__ agg)
{
    int gt = blockIdx.x * 256 + threadIdx.x;
    int n = gt >> 6;
    int c = threadIdx.x & 63;
    if (n >= N_NODES) return;
    int nu = __builtin_amdgcn_readfirstlane(n);   // force SGPR edge-list walk
    int start = (nu == 0) ? 0 : offs[nu - 1];
    int end = offs[nu];
    float acc = 0.f;
    int i = start;
    int2 p = (i < end) ? eid2[i] : make_int2(0, 0);
    while (i < end) {
        int2 cur = p;
        if (i + 1 < end) p = eid2[i + 1];          // prefetch next
        float m = x[(size_t)cur.y * HID + c] + ea[(size_t)cur.x * HID + c];
        acc += fmaxf(m, 0.f);
        ++i;
    }
    agg[(size_t)n * HID + c] = acc;
}

// Per-node MLP, outer-product form, weights staged in LDS, in-place on x.
// o = (relu?)(W2 @ relu(W1 @ (agg+x) + b1) + b2) + x
__global__ __launch_bounds__(256, 2) void mlp_kernel(
    const float* __restrict__ agg,
    const float* __restrict__ W1, const float* __restrict__ b1,
    const float* __restrict__ W2, const float* __restrict__ b2,
    float* __restrict__ x, int last_relu)
{
    __shared__ float sW1[HID * HID];
    __shared__ float sW2T[HID * HID];
    __shared__ float sb1[HID];
    int tid = threadIdx.x;
    for (int idx = tid; idx < HID * HID; idx += 256) {
        sW1[idx] = W1[idx];
        int r = idx >> 6, col = idx & 63;
        sW2T[col * HID + r] = W2[idx];   // transpose so layer-2 reads rows
    }
    if (tid < HID) sb1[tid] = b1[tid];
    __syncthreads();

    int n = blockIdx.x * 256 + tid;
    if (n >= N_NODES) return;

    const float4* ap = (const float4*)(agg + (size_t)n * HID);
    const float4* xp = (const float4*)(x + (size_t)n * HID);

    float in[HID];
#pragma unroll
    for (int c = 0; c < 16; ++c) {
        float4 a = ap[c], b = xp[c];
        in[4*c+0] = a.x + b.x;
        in[4*c+1] = a.y + b.y;
        in[4*c+2] = a.z + b.z;
        in[4*c+3] = a.w + b.w;
    }

    float o[HID];
    const float4* b2p = (const float4*)b2;
#pragma unroll
    for (int c = 0; c < 16; ++c) {
        float4 b = b2p[c];
        o[4*c+0] = b.x; o[4*c+1] = b.y; o[4*c+2] = b.z; o[4*c+3] = b.w;
    }

    for (int j = 0; j < HID; ++j) {
        const float4* w1p = (const float4*)(sW1 + j * HID);
        float a0 = 0.f, a1 = 0.f, a2 = 0.f, a3 = 0.f;  // break dep chain 4-way
#pragma unroll
        for (int c = 0; c < 16; c += 4) {
            float4 wa = w1p[c+0], wb = w1p[c+1], wc = w1p[c+2], wd = w1p[c+3];
            a0 += in[4*c+ 0]*wa.x + in[4*c+ 1]*wa.y + in[4*c+ 2]*wa.z + in[4*c+ 3]*wa.w;
            a1 += in[4*c+ 4]*wb.x + in[4*c+ 5]*wb.y + in[4*c+ 6]*wb.z + in[4*c+ 7]*wb.w;
            a2 += in[4*c+ 8]*wc.x + in[4*c+ 9]*wc.y + in[4*c+10]*wc.z + in[4*c+11]*wc.w;
            a3 += in[4*c+12]*wd.x + in[4*c+13]*wd.y + in[4*c+14]*wd.z + in[4*c+15]*wd.w;
        }
        float h = fmaxf((a0 + a1) + (a2 + a3) + sb1[j], 0.f);
        const float4* w2p = (const float4*)(sW2T + j * HID);
#pragma unroll
        for (int c = 0; c < 16; ++c) {
            float4 w = w2p[c];
            o[4*c+0] += h * w.x;
            o[4*c+1] += h * w.y;
            o[4*c+2] += h * w.z;
            o[4*c+3] += h * w.w;
        }
    }

    float* orow = x + (size_t)n * HID;   // in-place: row-private
#pragma unroll
    for (int c = 0; c < 16; ++c) {
        float4 xv = xp[c];
        float4 r;
        r.x = (last_relu ? fmaxf(o[4*c+0], 0.f) : o[4*c+0]) + xv.x;
        r.y = (last_relu ? fmaxf(o[4*c+1], 0.f) : o[4*c+1]) + xv.y;
        r.z = (last_relu ? fmaxf(o[4*c+2], 0.f) : o[4*c+2]) + xv.z;
        r.w = (last_relu ? fmaxf(o[4*c+3], 0.f) : o[4*c+3]) + xv.w;
        ((float4*)orow)[c] = r;
    }
}

extern "C" void kernel_launch(void* const* d_in, const int* in_sizes, int n_in,
                              void* d_out, int out_size, void* d_ws, size_t ws_size,
                              hipStream_t stream) {
    const float* node_emb = (const float*)d_in[0];
    const float* W1 = (const float*)d_in[1];
    const float* b1 = (const float*)d_in[2];
    const float* W2 = (const float*)d_in[3];
    const float* b2 = (const float*)d_in[4];
    const float* ea = (const float*)d_in[5];
    const int* z = (const int*)d_in[6];
    const int* ei = (const int*)d_in[7];
    const int* src = ei;            // edge_index[0] = message sender
    const int* dst = ei + N_EDGES;  // edge_index[1] = aggregation target

    float* x = (float*)d_out;                       // node features live here
    float* agg = (float*)d_ws;                      // 25.6 MB
    int2* eid2 = (int2*)((char*)d_ws + (size_t)N_NODES * HID * sizeof(float)); // 8 MB
    int* offs = (int*)(eid2 + N_EDGES);             // 0.4 MB

    const int eb = (N_EDGES + 255) / 256;            // 3907
    const int gather_blocks = (N_NODES * 16) / 256;  // 6250
    const int nodewave_blocks = (N_NODES * 64) / 256; // 25000
    const int mlp_blocks = (N_NODES + 255) / 256;    // 391

    // ---- CSR build (once, reused by all 3 convs) ----
    hipMemsetAsync(offs, 0, N_NODES * sizeof(int), stream);
    gather_kernel<<<gather_blocks, 256, 0, stream>>>(node_emb, z, x);
    hist_kernel<<<eb, 256, 0, stream>>>(dst, offs);
    scan_kernel<<<1, 1024, 0, stream>>>(offs);
    fill_kernel<<<eb, 256, 0, stream>>>(src, dst, offs, eid2);
    sort_kernel<<<nodewave_blocks, 256, 0, stream>>>(offs, eid2);

    // ---- 3 convs, x updated in place in d_out ----
    for (int conv = 0; conv < 3; ++conv) {
        agg_kernel<<<nodewave_blocks, 256, 0, stream>>>(x, ea, eid2, offs, agg);
        mlp_kernel<<<mlp_blocks, 256, 0, stream>>>(
            agg, W1 + conv * HID * HID, b1 + conv * HID,
            W2 + conv * HID * HID, b2 + conv * HID,
            x, conv < 2 ? 1 : 0);
    }
}